// Round 13
// baseline (61.235 us; speedup 1.0000x reference)
//
#include <hip/hip_runtime.h>

// Problem constants (match reference file)
#define S_LEN 512
#define B_SZ  512
#define D_DIM 256
#define SEP_ID 13
#define PAD_ID 1

typedef float f32x4 __attribute__((ext_vector_type(4)));

// Single fused kernel, column-slab decomposition: block = one batch column b.
// Phase A (wave 0): R6's proven Kogge-Stone inner-padding scan for column b,
// packing (tok | (pidx+1)<<16) into LDS (pidx+1==0 means skip).
// Phase B (all 4 waves): wave w writes output rows s = w*128..w*128+127 for
// this column: out[s*B+b][:] = tw[tok] + pe[pidx] (row 0 of tw is zero, and
// skip rows add nothing). 2 gathers + 1 store per 1KB row, as proven in R6.
__global__ void __launch_bounds__(256)
emb_onekernel(const int* __restrict__ seq,
              const float* __restrict__ tw,
              const float* __restrict__ pe,
              float* __restrict__ out) {
    const int b    = blockIdx.x;            // column 0..511
    const int lane = threadIdx.x & 63;
    const int w    = threadIdx.x >> 6;      // wave 0..3

    __shared__ unsigned meta[S_LEN];        // tok | (pidx+1)<<16

    if (w == 0) {
        // ---- Phase A: wave-scan of column b (identical math to R6) ----
        const int s0 = lane * (S_LEN / 64);     // 8 positions per lane
        int toks[8];
#pragma unroll
        for (int k = 0; k < 8; ++k) toks[k] = seq[(s0 + k) * B_SZ + b];

        // Local transfer function f(p) = A | (p & B)
        unsigned A = 0u, Bf = 1u;
#pragma unroll
        for (int k = 0; k < 8; ++k) {
            unsigned a  = (toks[k] == SEP_ID) ? 1u : 0u;
            unsigned bb = (toks[k] == PAD_ID) ? 1u : 0u;
            A  = a | (A & bb);
            Bf = Bf & bb;
        }

        // Inclusive Kogge-Stone scan of function composition
        unsigned incA = A, incB = Bf;
        for (int d = 1; d < 64; d <<= 1) {
            unsigned Al = __shfl_up(incA, d, 64);
            unsigned Bl = __shfl_up(incB, d, 64);
            if (lane >= d) {
                incA = incA | (Al & incB);
                incB = Bl & incB;
            }
        }
        unsigned pin = __shfl_up(incA, 1, 64);
        if (lane == 0) pin = 0u;

        // Recompute the 8 steps with the true incoming state
        unsigned p = pin, skipbits = 0u;
        int cnt = 0;
#pragma unroll
        for (int k = 0; k < 8; ++k) {
            unsigned a  = (toks[k] == SEP_ID) ? 1u : 0u;
            unsigned bb = (toks[k] == PAD_ID) ? 1u : 0u;
            unsigned skip = p & bb;
            skipbits |= skip << k;
            cnt += (int)skip;
            p = a | skip;
        }

        // Exclusive prefix sum of per-lane skip counts
        int pref = cnt;
        for (int d = 1; d < 64; d <<= 1) {
            int v = __shfl_up(pref, d, 64);
            if (lane >= d) pref += v;
        }
        pref -= cnt;

        int pad = pref;
#pragma unroll
        for (int k = 0; k < 8; ++k) {
            int s = s0 + k;
            unsigned skip = (skipbits >> k) & 1u;
            unsigned p1 = skip ? 0u : (unsigned)(s - pad + 1);  // pidx+1
            meta[s] = (unsigned)toks[k] | (p1 << 16);
            pad += (int)skip;
        }
    }
    __syncthreads();

    // ---- Phase B: write 128 rows per wave (2 gathers + 1 store / row) ----
    const unsigned doff = (unsigned)lane * 4u;
    float* ob = out + (size_t)b * D_DIM + doff;

#pragma unroll 8
    for (int i = 0; i < S_LEN / 4; ++i) {
        const int s = w * (S_LEN / 4) + i;
        const unsigned m   = meta[s];            // uniform addr -> broadcast
        const unsigned tok = m & 0xFFFFu;
        const int      p1  = (int)(m >> 16);

        const f32x4 tv = *(const f32x4*)(tw + (size_t)tok * D_DIM + doff);
        const int   pc = (p1 > 0) ? (p1 - 1) : 0;
        const f32x4 pv = *(const f32x4*)(pe + (size_t)pc * D_DIM + doff);
        const float pm = (p1 == 0) ? 0.0f : 1.0f;

        *(f32x4*)(ob + (size_t)s * B_SZ * D_DIM) = tv + pv * pm;
    }
}

extern "C" void kernel_launch(void* const* d_in, const int* in_sizes, int n_in,
                              void* d_out, int out_size, void* d_ws, size_t ws_size,
                              hipStream_t stream) {
    const int*   seq = (const int*)d_in[0];    // [S, B] int32
    const float* tw  = (const float*)d_in[1];  // [VOCAB, D] f32
    const float* pe  = (const float*)d_in[2];  // [MAX_LEN, D] f32
    float* out = (float*)d_out;                // [S, B, D] f32

    // One kernel: 512 blocks (one per column) x 256 threads.
    emb_onekernel<<<dim3(B_SZ), dim3(256), 0, stream>>>(seq, tw, pe, out);
}

// Round 14
// 53.577 us; speedup vs baseline: 1.1429x; 1.1429x over previous
//
#include <hip/hip_runtime.h>

// Problem constants (match reference file)
#define S_LEN 512
#define B_SZ  512
#define D_DIM 256
#define SEP_ID 13
#define PAD_ID 1

#define NTHR   256
#define ROWS_PER_WAVE 32
#define ROWS_PER_BLOCK 128                            // 4 waves x 32 rows
#define NROWS  (S_LEN * B_SZ)                         // 262144
#define NBLK_P 512                                    // persistent-ish grid
#define CHUNKS (NROWS / (NBLK_P * ROWS_PER_BLOCK))    // 4 sequential chunks

typedef float f32x4 __attribute__((ext_vector_type(4)));

// Kernel 1: wave-parallel inner-padding state machine (proven R6 version).
__global__ void emb_scan_wave(const int* __restrict__ seq,
                              int* __restrict__ idx) {
    const int lane = threadIdx.x & 63;
    const int b = blockIdx.x * (blockDim.x >> 6) + (threadIdx.x >> 6);
    if (b >= B_SZ) return;

    const int s0 = lane * (S_LEN / 64);      // 8 positions per lane
    int toks[8];
#pragma unroll
    for (int k = 0; k < 8; ++k) toks[k] = seq[(s0 + k) * B_SZ + b];

    // Local transfer function over this lane's 8 tokens: f(p) = A | (p & B)
    unsigned A = 0u, Bf = 1u;
#pragma unroll
    for (int k = 0; k < 8; ++k) {
        unsigned a  = (toks[k] == SEP_ID) ? 1u : 0u;
        unsigned bb = (toks[k] == PAD_ID) ? 1u : 0u;
        A  = a | (A & bb);
        Bf = Bf & bb;
    }

    // Inclusive Kogge-Stone scan of function composition (lower lanes first)
    unsigned incA = A, incB = Bf;
    for (int d = 1; d < 64; d <<= 1) {
        unsigned Al = __shfl_up(incA, d, 64);
        unsigned Bl = __shfl_up(incB, d, 64);
        if (lane >= d) {
            incA = incA | (Al & incB);
            incB = Bl & incB;
        }
    }
    unsigned pin = __shfl_up(incA, 1, 64);
    if (lane == 0) pin = 0u;

    // Recompute the 8 steps with the true incoming state
    unsigned p = pin, skipbits = 0u;
    int cnt = 0;
#pragma unroll
    for (int k = 0; k < 8; ++k) {
        unsigned a  = (toks[k] == SEP_ID) ? 1u : 0u;
        unsigned bb = (toks[k] == PAD_ID) ? 1u : 0u;
        unsigned skip = p & bb;
        skipbits |= skip << k;
        cnt += (int)skip;
        p = a | skip;
    }

    // Exclusive prefix sum of per-lane skip counts -> pad_num at lane start
    int pref = cnt;
    for (int d = 1; d < 64; d <<= 1) {
        int v = __shfl_up(pref, d, 64);
        if (lane >= d) pref += v;
    }
    pref -= cnt;

    int pad = pref;
#pragma unroll
    for (int k = 0; k < 8; ++k) {
        int s = s0 + k;
        unsigned skip = (skipbits >> k) & 1u;
        idx[s * B_SZ + b] = skip ? -1 : (s - pad);
        pad += (int)skip;
    }
}

// Kernel 2: fused gather+add — R6 body, quasi-persistent grid (512 blocks x
// 4 chunks). Steady state measured at 6.9 TB/s (86% HBM peak) = fill rate.
__global__ void __launch_bounds__(NTHR)
emb_fused_kernel(const int* __restrict__ seq,
                 const float* __restrict__ tw,
                 const float* __restrict__ pe,
                 const int* __restrict__ idx,
                 float* __restrict__ out) {
    const unsigned lane  = threadIdx.x & 63u;
    const unsigned wid_s = (unsigned)__builtin_amdgcn_readfirstlane(threadIdx.x >> 6);
    const unsigned doff  = lane * 4u;

    for (unsigned c = 0; c < CHUNKS; ++c) {
        const unsigned row0 = (c * NBLK_P + blockIdx.x) * ROWS_PER_BLOCK
                              + wid_s * ROWS_PER_WAVE;

        const int* __restrict__ tokp  = seq + row0;   // wave-uniform pointers
        const int* __restrict__ pidxp = idx + row0;
        float* orow = out + (size_t)row0 * D_DIM + doff;

#pragma unroll 8
        for (int it = 0; it < ROWS_PER_WAVE; ++it) {
            const int tok  = tokp[it];    // uniform addr -> s_load
            const int pidx = pidxp[it];   // uniform addr -> s_load

            const f32x4 tv = *(const f32x4*)(tw + (size_t)tok * D_DIM + doff);
            const int   pc = (pidx < 0) ? 0 : pidx;
            const f32x4 pv = *(const f32x4*)(pe + (size_t)pc * D_DIM + doff);
            const float pm = (pidx < 0) ? 0.0f : 1.0f;

            f32x4 o = tv + pv * pm;
            *(f32x4*)(orow + (size_t)it * D_DIM) = o;
        }
    }
}

extern "C" void kernel_launch(void* const* d_in, const int* in_sizes, int n_in,
                              void* d_out, int out_size, void* d_ws, size_t ws_size,
                              hipStream_t stream) {
    const int*   seq = (const int*)d_in[0];    // [S, B] int32
    const float* tw  = (const float*)d_in[1];  // [VOCAB, D] f32
    const float* pe  = (const float*)d_in[2];  // [MAX_LEN, D] f32
    float* out = (float*)d_out;                // [S, B, D] f32
    int*   idx = (int*)d_ws;                   // [S, B] int32 scratch (1 MiB)

    // 1) wave-parallel scan: 512 columns, 1 wave each -> 128 blocks x 256
    emb_scan_wave<<<dim3(B_SZ / 4), dim3(256), 0, stream>>>(seq, idx);

    // 2) fused gather+add: 512 blocks x 4 chunks
    emb_fused_kernel<<<dim3(NBLK_P), dim3(NTHR), 0, stream>>>(seq, tw, pe, idx, out);
}